// Round 3
// baseline (438.213 us; speedup 1.0000x reference)
//
#include <hip/hip_runtime.h>
#include <math.h>

#define N_NODES 20000
#define N_EDGES 100000
// dims: node 64, edge 32, heads 2, out 64 -> H*D = 128 everywhere

__device__ __forceinline__ float rl_f(float v, int l) {
    return __uint_as_float(__builtin_amdgcn_readlane(__float_as_uint(v), l));
}
__device__ __forceinline__ int rl_i(int v, int l) {
    return __builtin_amdgcn_readlane(v, l);
}
__device__ __forceinline__ float lrelu(float x) { return x > 0.f ? x : 0.2f * x; }

// ---------------------------------------------------------------------------
// CSR build: count(+pos) -> parallel 2-kernel scan -> scatter
// ---------------------------------------------------------------------------
__global__ __launch_bounds__(256) void count_kernel(const int* __restrict__ dst,
                                                    int* __restrict__ cnt,
                                                    int* __restrict__ pos) {
    int e = blockIdx.x * 256 + threadIdx.x;
    if (e < N_EDGES) pos[e] = atomicAdd(&cnt[dst[e]], 1);
}

// scanA: per-block sums of cnt (79 blocks x 256)
__global__ __launch_bounds__(256) void scanA_kernel(const int* __restrict__ cnt,
                                                    int* __restrict__ bsum) {
    __shared__ int wsum[4];
    const int tid = threadIdx.x;
    int idx = blockIdx.x * 256 + tid;
    int v = (idx < N_NODES) ? cnt[idx] : 0;
    int s = v;
#pragma unroll
    for (int off = 32; off; off >>= 1) s += __shfl_xor(s, off);
    if ((tid & 63) == 0) wsum[tid >> 6] = s;
    __syncthreads();
    if (tid == 0) bsum[blockIdx.x] = wsum[0] + wsum[1] + wsum[2] + wsum[3];
}

// scanC: block b scans its 256-chunk in LDS, adds sum of bsum[j<b]
__global__ __launch_bounds__(256) void scanC_kernel(const int* __restrict__ cnt,
                                                    const int* __restrict__ bsum,
                                                    int* __restrict__ row_ptr) {
    __shared__ int sdata[256];
    __shared__ int s_boff;
    const int tid = threadIdx.x;
    const int b = blockIdx.x;
    int idx = b * 256 + tid;
    int v = (idx < N_NODES) ? cnt[idx] : 0;
    sdata[tid] = v;
    // first wave: block offset = sum of preceding block sums (gridDim <= 128)
    if (tid < 64) {
        int a = (tid < b) ? bsum[tid] : 0;
        if (64 + tid < b) a += bsum[64 + tid];
#pragma unroll
        for (int off = 32; off; off >>= 1) a += __shfl_xor(a, off);
        if (tid == 0) s_boff = a;
    }
    __syncthreads();
    // Hillis-Steele inclusive scan over 256
    for (int off = 1; off < 256; off <<= 1) {
        int t_ = (tid >= off) ? sdata[tid - off] : 0;
        __syncthreads();
        sdata[tid] += t_;
        __syncthreads();
    }
    if (idx < N_NODES) row_ptr[idx] = s_boff + sdata[tid] - v;
    if (b == 0 && tid == 0) row_ptr[N_NODES] = N_EDGES;
}

__global__ __launch_bounds__(256) void scatter_kernel(const int* __restrict__ dst,
                                                      const int* __restrict__ row_ptr,
                                                      const int* __restrict__ pos,
                                                      int* __restrict__ edge_idx) {
    int e = blockIdx.x * 256 + threadIdx.x;
    if (e < N_EDGES) edge_idx[row_ptr[dst[e]] + pos[e]] = e;
}

// ---------------------------------------------------------------------------
// Q[k*8 + L*2 + h] = sum_d We_L[k*128 + h*64 + d] * ae_L[h*64 + d]
// ---------------------------------------------------------------------------
__global__ __launch_bounds__(256) void q_kernel(const float* __restrict__ We0, const float* __restrict__ ae0,
                                                const float* __restrict__ We1, const float* __restrict__ ae1,
                                                const float* __restrict__ We2, const float* __restrict__ ae2,
                                                const float* __restrict__ We3, const float* __restrict__ ae3,
                                                float* __restrict__ Q) {
    const int t = threadIdx.x;  // 256 = 32 k * 8 o
    const int k = t >> 3, o = t & 7, L = o >> 1, h = o & 1;
    const float* We = (L == 0) ? We0 : (L == 1) ? We1 : (L == 2) ? We2 : We3;
    const float* ae = (L == 0) ? ae0 : (L == 1) ? ae1 : (L == 2) ? ae2 : ae3;
    float acc = 0.f;
#pragma unroll 8
    for (int d = 0; d < 64; d++) acc = fmaf(We[k * 128 + h * 64 + d], ae[h * 64 + d], acc);
    Q[t] = acc;
}

// ---------------------------------------------------------------------------
// EE[e*8+o] = Efeat[e,:] . Q[:,o]   (all 4 layers x 2 heads at once)
// ---------------------------------------------------------------------------
__global__ __launch_bounds__(256) void ee_kernel(const float* __restrict__ Efeat,
                                                 const float* __restrict__ Q,
                                                 float* __restrict__ EE) {
    __shared__ float QS[256];
    const int tid = threadIdx.x;
    QS[tid] = Q[tid];
    __syncthreads();
    const int e = blockIdx.x * 32 + (tid >> 3);
    const int o = tid & 7;
    if (e >= N_EDGES) return;
    const float4* E4 = (const float4*)(Efeat + (size_t)e * 32);
    float acc = 0.f;
#pragma unroll
    for (int k4 = 0; k4 < 8; k4++) {
        float4 v = E4[k4];
        acc = fmaf(v.x, QS[(k4 * 4 + 0) * 8 + o], acc);
        acc = fmaf(v.y, QS[(k4 * 4 + 1) * 8 + o], acc);
        acc = fmaf(v.z, QS[(k4 * 4 + 2) * 8 + o], acc);
        acc = fmaf(v.w, QS[(k4 * 4 + 3) * 8 + o], acc);
    }
    EE[e * 8 + o] = acc;
}

// ---------------------------------------------------------------------------
// Wcomb[j,c] = sum_i W_e2d[i,j] * Wn[i,c]
// ---------------------------------------------------------------------------
__global__ __launch_bounds__(256) void comb_kernel(const float* __restrict__ W_e2d,
                                                   const float* __restrict__ Wn,
                                                   float* __restrict__ Wcomb) {
    int idx = blockIdx.x * 256 + threadIdx.x;
    int j = idx >> 7, c = idx & 127;
    float acc = 0.f;
#pragma unroll 8
    for (int i = 0; i < 64; i++) acc = fmaf(W_e2d[i * 64 + j], Wn[i * 128 + c], acc);
    Wcomb[idx] = acc;
}

// ---------------------------------------------------------------------------
// P4[L*256 + k*4 + o]: o=0: Wn@al(h0), 1: Wn@al(h1), 2: Wn@ar(h0), 3: Wn@ar(h1)
// (folds the node GEMM out of the attention-logit path: el = x . P4col)
// one block per layer L
// ---------------------------------------------------------------------------
__global__ __launch_bounds__(256) void p4_kernel(const float* __restrict__ Wn0, const float* __restrict__ al0, const float* __restrict__ ar0,
                                                 const float* __restrict__ Wn1, const float* __restrict__ al1, const float* __restrict__ ar1,
                                                 const float* __restrict__ Wn2, const float* __restrict__ al2, const float* __restrict__ ar2,
                                                 const float* __restrict__ Wn3, const float* __restrict__ al3, const float* __restrict__ ar3,
                                                 float* __restrict__ P4) {
    const int L = blockIdx.x;
    const float* Wn = (L == 0) ? Wn0 : (L == 1) ? Wn1 : (L == 2) ? Wn2 : Wn3;
    const float* al = (L == 0) ? al0 : (L == 1) ? al1 : (L == 2) ? al2 : al3;
    const float* ar = (L == 0) ? ar0 : (L == 1) ? ar1 : (L == 2) ? ar2 : ar3;
    const int t = threadIdx.x;  // 64 k * 4 o
    const int k = t >> 2, o = t & 3;
    const float* a = (o & 2) ? ar : al;
    const int h = o & 1;
    float acc = 0.f;
#pragma unroll 8
    for (int d = 0; d < 64; d++) acc = fmaf(Wn[k * 128 + h * 64 + d], a[h * 64 + d], acc);
    P4[L * 256 + t] = acc;
}

// ---------------------------------------------------------------------------
// elr: EL2[n]=(el0,el1), ER2[n]=(er0,er1) = x[n,:] . P4 columns
// ---------------------------------------------------------------------------
__global__ __launch_bounds__(256) void elr_kernel(const float* __restrict__ X,
                                                  const float* __restrict__ P4,
                                                  float2* __restrict__ EL2,
                                                  float2* __restrict__ ER2) {
    const int tid = threadIdx.x;
    const int lane = tid & 63;
    const int wave = tid >> 6;
    const float4 p = ((const float4*)P4)[lane];
    for (int node = blockIdx.x * 4 + wave; node < N_NODES; node += gridDim.x * 4) {
        float xv = X[node * 64 + lane];
        float e0 = xv * p.x, e1 = xv * p.y, f0 = xv * p.z, f1 = xv * p.w;
#pragma unroll
        for (int off = 32; off; off >>= 1) {
            e0 += __shfl_xor(e0, off);
            e1 += __shfl_xor(e1, off);
            f0 += __shfl_xor(f0, off);
            f1 += __shfl_xor(f1, off);
        }
        if (lane == 0) {
            EL2[node] = make_float2(e0, e1);
            ER2[node] = make_float2(f0, f1);
        }
    }
}

// ---------------------------------------------------------------------------
// gather (FT-free): per edge accumulate weighted x[src] rows (aX0,aX1) and
// weighted Efeat rows (aE, packed); apply Wn and We once per node in epilogue.
// ---------------------------------------------------------------------------
__global__ __launch_bounds__(256) void gather_kernel(const float* __restrict__ X,
                                                     const float2* __restrict__ EL2,
                                                     const float2* __restrict__ ER2,
                                                     const float* __restrict__ Efeat,
                                                     const int* __restrict__ SRC,
                                                     const int* __restrict__ row_ptr,
                                                     const int* __restrict__ edge_idx,
                                                     const float2* __restrict__ EE2,
                                                     const int L,
                                                     const float* __restrict__ Wn,   // [64,128]
                                                     const float* __restrict__ We,   // [32,128]
                                                     const float* __restrict__ bias, // [2,64]
                                                     float* __restrict__ OUT) {      // [N,64]
    __shared__ float4 WnS4[32 * 64];  // 32 KB
    __shared__ float4 WeS4[16 * 64];  // 16 KB
    const int tid = threadIdx.x;
    for (int idx = tid; idx < 32 * 64; idx += 256) {
        int k2 = idx >> 6, l = idx & 63;
        WnS4[idx] = make_float4(Wn[(2 * k2) * 128 + l], Wn[(2 * k2) * 128 + 64 + l],
                                Wn[(2 * k2 + 1) * 128 + l], Wn[(2 * k2 + 1) * 128 + 64 + l]);
    }
    for (int idx = tid; idx < 16 * 64; idx += 256) {
        int k2 = idx >> 6, l = idx & 63;
        WeS4[idx] = make_float4(We[(2 * k2) * 128 + l], We[(2 * k2) * 128 + 64 + l],
                                We[(2 * k2 + 1) * 128 + l], We[(2 * k2 + 1) * 128 + 64 + l]);
    }
    __syncthreads();
    const int lane = tid & 63;
    const int wave = tid >> 6;
    const float b0 = bias[lane], b1 = bias[64 + lane];
    const float NEG_INF = -__builtin_inff();

    for (int node = blockIdx.x * 4 + wave; node < N_NODES; node += gridDim.x * 4) {
        const int beg = row_ptr[node], end = row_ptr[node + 1];
        const int deg = end - beg;
        float2 er = ER2[node];
        float l0 = 0.f, l1 = 0.f, aX0 = 0.f, aX1 = 0.f, aE = 0.f;

        if (deg <= 64) {
            // --- fast path: all edges lane-parallel ---
            int eid = 0, sn = 0;
            float lg0 = NEG_INF, lg1 = NEG_INF;
            if (lane < deg) {
                eid = edge_idx[beg + lane];
                sn = SRC[eid];
                float2 ee = EE2[eid * 4 + L];
                float2 el = EL2[sn];
                lg0 = lrelu(el.x + er.x + ee.x);
                lg1 = lrelu(el.y + er.y + ee.y);
            }
            float m0 = lg0, m1 = lg1;
#pragma unroll
            for (int off = 32; off; off >>= 1) {
                m0 = fmaxf(m0, __shfl_xor(m0, off));
                m1 = fmaxf(m1, __shfl_xor(m1, off));
            }
            float w0 = (lane < deg) ? __expf(lg0 - m0) : 0.f;
            float w1 = (lane < deg) ? __expf(lg1 - m1) : 0.f;
            l0 = w0;
            l1 = w1;
#pragma unroll
            for (int off = 32; off; off >>= 1) {
                l0 += __shfl_xor(l0, off);
                l1 += __shfl_xor(l1, off);
            }
            for (int t = 0; t < deg; t++) {
                int st = rl_i(sn, t);
                int et = rl_i(eid, t);
                float w0t = rl_f(w0, t);
                float w1t = rl_f(w1, t);
                float xv = X[st * 64 + lane];
                aX0 = fmaf(w0t, xv, aX0);
                aX1 = fmaf(w1t, xv, aX1);
                float wEt = (lane < 32) ? w0t : w1t;
                aE = fmaf(wEt, Efeat[et * 32 + (lane & 31)], aE);
            }
        } else {
            // --- general path: chunked two-pass ---
            float m0 = NEG_INF, m1 = NEG_INF;
            for (int c = beg; c < end; c += 64) {
                int j = c + lane;
                float lg0 = NEG_INF, lg1 = NEG_INF;
                if (j < end) {
                    int eid = edge_idx[j];
                    int sn = SRC[eid];
                    float2 ee = EE2[eid * 4 + L];
                    float2 el = EL2[sn];
                    lg0 = lrelu(el.x + er.x + ee.x);
                    lg1 = lrelu(el.y + er.y + ee.y);
                }
#pragma unroll
                for (int off = 32; off; off >>= 1) {
                    lg0 = fmaxf(lg0, __shfl_xor(lg0, off));
                    lg1 = fmaxf(lg1, __shfl_xor(lg1, off));
                }
                m0 = fmaxf(m0, lg0);
                m1 = fmaxf(m1, lg1);
            }
            for (int c = beg; c < end; c += 64) {
                int j = c + lane;
                int eid = 0, sn = 0;
                float lg0 = NEG_INF, lg1 = NEG_INF;
                if (j < end) {
                    eid = edge_idx[j];
                    sn = SRC[eid];
                    float2 ee = EE2[eid * 4 + L];
                    float2 el = EL2[sn];
                    lg0 = lrelu(el.x + er.x + ee.x);
                    lg1 = lrelu(el.y + er.y + ee.y);
                }
                float w0 = (j < end) ? __expf(lg0 - m0) : 0.f;
                float w1 = (j < end) ? __expf(lg1 - m1) : 0.f;
                float s0 = w0, s1 = w1;
#pragma unroll
                for (int off = 32; off; off >>= 1) {
                    s0 += __shfl_xor(s0, off);
                    s1 += __shfl_xor(s1, off);
                }
                l0 += s0;
                l1 += s1;
                int nch = (end - c) < 64 ? (end - c) : 64;
                for (int t = 0; t < nch; t++) {
                    int st = rl_i(sn, t);
                    int et = rl_i(eid, t);
                    float w0t = rl_f(w0, t);
                    float w1t = rl_f(w1, t);
                    float xv = X[st * 64 + lane];
                    aX0 = fmaf(w0t, xv, aX0);
                    aX1 = fmaf(w1t, xv, aX1);
                    float wEt = (lane < 32) ? w0t : w1t;
                    aE = fmaf(wEt, Efeat[et * 32 + (lane & 31)], aE);
                }
            }
        }

        // --- epilogue: r = aX @ Wn + aE @ We (per head), then mean + bias ---
        float r0 = 0.f, r1 = 0.f;
#pragma unroll
        for (int k2 = 0; k2 < 32; k2++) {
            float4 w4 = WnS4[k2 * 64 + lane];
            float xa0 = rl_f(aX0, 2 * k2);
            float xa1 = rl_f(aX0, 2 * k2 + 1);
            float xb0 = rl_f(aX1, 2 * k2);
            float xb1 = rl_f(aX1, 2 * k2 + 1);
            r0 = fmaf(xa0, w4.x, r0);
            r1 = fmaf(xb0, w4.y, r1);
            r0 = fmaf(xa1, w4.z, r0);
            r1 = fmaf(xb1, w4.w, r1);
        }
#pragma unroll
        for (int k2 = 0; k2 < 16; k2++) {
            float4 w4 = WeS4[k2 * 64 + lane];
            float ea0 = rl_f(aE, 2 * k2);
            float ea1 = rl_f(aE, 2 * k2 + 1);
            float eb0 = rl_f(aE, 32 + 2 * k2);
            float eb1 = rl_f(aE, 32 + 2 * k2 + 1);
            r0 = fmaf(ea0, w4.x, r0);
            r1 = fmaf(eb0, w4.y, r1);
            r0 = fmaf(ea1, w4.z, r0);
            r1 = fmaf(eb1, w4.w, r1);
        }
        const float inv0 = l0 > 0.f ? 1.f / l0 : 0.f;
        const float inv1 = l1 > 0.f ? 1.f / l1 : 0.f;
        OUT[node * 64 + lane] = 0.5f * (r0 * inv0 + b0 + r1 * inv1 + b1);
    }
}

// ---------------------------------------------------------------------------
extern "C" void kernel_launch(void* const* d_in, const int* in_sizes, int n_in,
                              void* d_out, int out_size, void* d_ws, size_t ws_size,
                              hipStream_t stream) {
    const float* x = (const float*)d_in[0];
    const float* e = (const float*)d_in[1];
    const int* src = (const int*)d_in[2];
    const int* dst = (const int*)d_in[3];

    // Only the LAST snapshot contributes to the output (decoded[-1]).
    const float* x1 = x + (size_t)1 * N_NODES * 64;
    const float* e1 = e + (size_t)1 * N_EDGES * 32;
    const int* src1 = src + N_EDGES;
    const int* dst1 = dst + N_EDGES;

    int we2d_idx, dec0_b, dec1_b;
    if (in_sizes[16] == 64 * 64 && in_sizes[17] == 64 * 128) {
        we2d_idx = 16; dec0_b = 17; dec1_b = 23;
    } else {
        dec0_b = 16; dec1_b = 22; we2d_idx = 28;
    }
    auto P = [&](int i) { return (const float*)d_in[i]; };

    // workspace layout (bytes, 16-aligned)
    char* ws = (char*)d_ws;
    int* cnt      = (int*)(ws + 0);          //    80,000
    int* row_ptr  = (int*)(ws + 80000);      //    80,004
    int* pos      = (int*)(ws + 160064);     //   400,000
    int* edge_idx = (int*)(ws + 560064);     //   400,000
    int* bsum     = (int*)(ws + 960064);     //     1,024
    float* q      = (float*)(ws + 961088);   //     1,024
    float* ee_all = (float*)(ws + 962112);   // 3,200,000
    float* p4_all = (float*)(ws + 4162112);  //     4,096
    float* el     = (float*)(ws + 4166208);  //   160,000
    float* er     = (float*)(ws + 4326208);  //   160,000
    float* h_a    = (float*)(ws + 4486208);  // 5,120,000
    float* h_b    = (float*)(ws + 9606208);  // 5,120,000
    float* wcomb  = (float*)(ws + 14726208); //    32,768
    // total ~14.76 MB

    hipMemsetAsync(cnt, 0, N_NODES * sizeof(int), stream);
    const int EB = (N_EDGES + 255) / 256;
    const int SB = (N_NODES + 255) / 256;  // 79
    count_kernel<<<EB, 256, 0, stream>>>(dst1, cnt, pos);
    scanA_kernel<<<SB, 256, 0, stream>>>(cnt, bsum);
    scanC_kernel<<<SB, 256, 0, stream>>>(cnt, bsum, row_ptr);
    scatter_kernel<<<EB, 256, 0, stream>>>(dst1, row_ptr, pos, edge_idx);

    // Per-edge attention pre-reductions for all 4 layers at once
    q_kernel<<<1, 256, 0, stream>>>(P(5), P(8), P(11), P(14),
                                    P(dec0_b + 1), P(dec0_b + 4),
                                    P(dec1_b + 1), P(dec1_b + 4), q);
    ee_kernel<<<(N_EDGES + 31) / 32, 256, 0, stream>>>(e1, q, ee_all);
    comb_kernel<<<32, 256, 0, stream>>>(P(we2d_idx), P(dec0_b + 0), wcomb);
    // P4 (logit projections) — after comb (layer 2 uses wcomb)
    p4_kernel<<<4, 256, 0, stream>>>(P(4), P(6), P(7),
                                     P(10), P(12), P(13),
                                     wcomb, P(dec0_b + 2), P(dec0_b + 3),
                                     P(dec1_b + 0), P(dec1_b + 2), P(dec1_b + 3),
                                     p4_all);

    const int NB = 1280;  // grid-stride: 5 blocks/CU

    auto run_layer = [&](const float* Xin, const float* Wn, const float* We_,
                         const float* b_, int L, float* Out) {
        elr_kernel<<<NB, 256, 0, stream>>>(Xin, p4_all + L * 256, (float2*)el,
                                           (float2*)er);
        gather_kernel<<<NB, 256, 0, stream>>>(Xin, (const float2*)el,
                                              (const float2*)er, e1, src1, row_ptr,
                                              edge_idx, (const float2*)ee_all, L,
                                              Wn, We_, b_, Out);
    };

    // ping-pong h_a/h_b (gather reads layer input edge-wise; no in-place)
    run_layer(x1, P(4), P(5), P(9), 0, h_a);
    run_layer(h_a, P(10), P(11), P(15), 1, h_b);
    run_layer(h_b, wcomb, P(dec0_b + 1), P(dec0_b + 5), 2, h_a);
    run_layer(h_a, P(dec1_b + 0), P(dec1_b + 1), P(dec1_b + 5), 3, (float*)d_out);
}

// Round 4
// 331.957 us; speedup vs baseline: 1.3201x; 1.3201x over previous
//
#include <hip/hip_runtime.h>
#include <math.h>

#define N_NODES 20000
#define N_EDGES 100000
// dims: node 64, edge 32, heads 2, out 64 -> H*D = 128 everywhere

__device__ __forceinline__ float rl_f(float v, int l) {
    return __uint_as_float(__builtin_amdgcn_readlane(__float_as_uint(v), l));
}
__device__ __forceinline__ int rl_i(int v, int l) {
    return __builtin_amdgcn_readlane(v, l);
}
__device__ __forceinline__ float lrelu(float x) { return x > 0.f ? x : 0.2f * x; }

// ---------------------------------------------------------------------------
// CSR build: count(+pos) -> parallel 2-kernel scan. (No scatter: all per-edge
// arrays are written directly in CSR order by permE/ee below.)
// ---------------------------------------------------------------------------
__global__ __launch_bounds__(256) void count_kernel(const int* __restrict__ dst,
                                                    int* __restrict__ cnt,
                                                    int* __restrict__ pos) {
    int e = blockIdx.x * 256 + threadIdx.x;
    if (e < N_EDGES) pos[e] = atomicAdd(&cnt[dst[e]], 1);
}

__global__ __launch_bounds__(256) void scanA_kernel(const int* __restrict__ cnt,
                                                    int* __restrict__ bsum) {
    __shared__ int wsum[4];
    const int tid = threadIdx.x;
    int idx = blockIdx.x * 256 + tid;
    int v = (idx < N_NODES) ? cnt[idx] : 0;
    int s = v;
#pragma unroll
    for (int off = 32; off; off >>= 1) s += __shfl_xor(s, off);
    if ((tid & 63) == 0) wsum[tid >> 6] = s;
    __syncthreads();
    if (tid == 0) bsum[blockIdx.x] = wsum[0] + wsum[1] + wsum[2] + wsum[3];
}

__global__ __launch_bounds__(256) void scanC_kernel(const int* __restrict__ cnt,
                                                    const int* __restrict__ bsum,
                                                    int* __restrict__ row_ptr) {
    __shared__ int sdata[256];
    __shared__ int s_boff;
    const int tid = threadIdx.x;
    const int b = blockIdx.x;
    int idx = b * 256 + tid;
    int v = (idx < N_NODES) ? cnt[idx] : 0;
    sdata[tid] = v;
    if (tid < 64) {
        int a = (tid < b) ? bsum[tid] : 0;
        if (64 + tid < b) a += bsum[64 + tid];
#pragma unroll
        for (int off = 32; off; off >>= 1) a += __shfl_xor(a, off);
        if (tid == 0) s_boff = a;
    }
    __syncthreads();
    for (int off = 1; off < 256; off <<= 1) {
        int t_ = (tid >= off) ? sdata[tid - off] : 0;
        __syncthreads();
        sdata[tid] += t_;
        __syncthreads();
    }
    if (idx < N_NODES) row_ptr[idx] = s_boff + sdata[tid] - v;
    if (b == 0 && tid == 0) row_ptr[N_NODES] = N_EDGES;
}

// ---------------------------------------------------------------------------
// permE: E_csr[j,32] = Efeat[e,32], src_csr[j] = src[e], j = CSR slot of e
// ---------------------------------------------------------------------------
__global__ __launch_bounds__(256) void permE_kernel(const float* __restrict__ Efeat,
                                                    const int* __restrict__ src,
                                                    const int* __restrict__ dst,
                                                    const int* __restrict__ pos,
                                                    const int* __restrict__ row_ptr,
                                                    float* __restrict__ E_csr,
                                                    int* __restrict__ src_csr) {
    int idx = blockIdx.x * 256 + threadIdx.x;
    int e = idx >> 5, c = idx & 31;
    if (e >= N_EDGES) return;
    int j = row_ptr[dst[e]] + pos[e];
    E_csr[(size_t)j * 32 + c] = Efeat[(size_t)e * 32 + c];
    if (c == 0) src_csr[j] = src[e];
}

// ---------------------------------------------------------------------------
// Q[k*8 + o], o = L*2+h : edge-attention projections for all 4 layers
// ---------------------------------------------------------------------------
__global__ __launch_bounds__(256) void q_kernel(const float* __restrict__ We0, const float* __restrict__ ae0,
                                                const float* __restrict__ We1, const float* __restrict__ ae1,
                                                const float* __restrict__ We2, const float* __restrict__ ae2,
                                                const float* __restrict__ We3, const float* __restrict__ ae3,
                                                float* __restrict__ Q) {
    const int t = threadIdx.x;
    const int k = t >> 3, o = t & 7, L = o >> 1, h = o & 1;
    const float* We = (L == 0) ? We0 : (L == 1) ? We1 : (L == 2) ? We2 : We3;
    const float* ae = (L == 0) ? ae0 : (L == 1) ? ae1 : (L == 2) ? ae2 : ae3;
    float acc = 0.f;
#pragma unroll 8
    for (int d = 0; d < 64; d++) acc = fmaf(We[k * 128 + h * 64 + d], ae[h * 64 + d], acc);
    Q[t] = acc;
}

// ---------------------------------------------------------------------------
// EE_csr[L][j][h] = Efeat[e,:] . Q[:,L,h]  written directly in CSR order
// ---------------------------------------------------------------------------
__global__ __launch_bounds__(256) void ee_kernel(const float* __restrict__ Efeat,
                                                 const int* __restrict__ dst,
                                                 const int* __restrict__ pos,
                                                 const int* __restrict__ row_ptr,
                                                 const float* __restrict__ Q,
                                                 float* __restrict__ EE_csr) {
    __shared__ float QS[256];
    const int tid = threadIdx.x;
    QS[tid] = Q[tid];
    __syncthreads();
    const int e = blockIdx.x * 32 + (tid >> 3);
    const int o = tid & 7;
    if (e >= N_EDGES) return;
    const int j = row_ptr[dst[e]] + pos[e];
    const float4* E4 = (const float4*)(Efeat + (size_t)e * 32);
    float acc = 0.f;
#pragma unroll
    for (int k4 = 0; k4 < 8; k4++) {
        float4 v = E4[k4];
        acc = fmaf(v.x, QS[(k4 * 4 + 0) * 8 + o], acc);
        acc = fmaf(v.y, QS[(k4 * 4 + 1) * 8 + o], acc);
        acc = fmaf(v.z, QS[(k4 * 4 + 2) * 8 + o], acc);
        acc = fmaf(v.w, QS[(k4 * 4 + 3) * 8 + o], acc);
    }
    EE_csr[(size_t)(o >> 1) * 2 * N_EDGES + (size_t)j * 2 + (o & 1)] = acc;
}

// ---------------------------------------------------------------------------
// Wcomb[j,c] = sum_i W_e2d[i,j] * Wn[i,c]
// ---------------------------------------------------------------------------
__global__ __launch_bounds__(256) void comb_kernel(const float* __restrict__ W_e2d,
                                                   const float* __restrict__ Wn,
                                                   float* __restrict__ Wcomb) {
    int idx = blockIdx.x * 256 + threadIdx.x;
    int j = idx >> 7, c = idx & 127;
    float acc = 0.f;
#pragma unroll 8
    for (int i = 0; i < 64; i++) acc = fmaf(W_e2d[i * 64 + j], Wn[i * 128 + c], acc);
    Wcomb[idx] = acc;
}

// ---------------------------------------------------------------------------
// P4[L*256 + k*4 + o]: o=0: Wn@al(h0), 1: Wn@al(h1), 2: Wn@ar(h0), 3: Wn@ar(h1)
// ---------------------------------------------------------------------------
__global__ __launch_bounds__(256) void p4_kernel(const float* __restrict__ Wn0, const float* __restrict__ al0, const float* __restrict__ ar0,
                                                 const float* __restrict__ Wn1, const float* __restrict__ al1, const float* __restrict__ ar1,
                                                 const float* __restrict__ Wn2, const float* __restrict__ al2, const float* __restrict__ ar2,
                                                 const float* __restrict__ Wn3, const float* __restrict__ al3, const float* __restrict__ ar3,
                                                 float* __restrict__ P4) {
    const int L = blockIdx.x;
    const float* Wn = (L == 0) ? Wn0 : (L == 1) ? Wn1 : (L == 2) ? Wn2 : Wn3;
    const float* al = (L == 0) ? al0 : (L == 1) ? al1 : (L == 2) ? al2 : al3;
    const float* ar = (L == 0) ? ar0 : (L == 1) ? ar1 : (L == 2) ? ar2 : ar3;
    const int t = threadIdx.x;
    const int k = t >> 2, o = t & 3;
    const float* a = (o & 2) ? ar : al;
    const int h = o & 1;
    float acc = 0.f;
#pragma unroll 8
    for (int d = 0; d < 64; d++) acc = fmaf(Wn[k * 128 + h * 64 + d], a[h * 64 + d], acc);
    P4[L * 256 + t] = acc;
}

// ---------------------------------------------------------------------------
// elr (layer 0 only): EL/ER from x1
// ---------------------------------------------------------------------------
__global__ __launch_bounds__(256) void elr_kernel(const float* __restrict__ X,
                                                  const float* __restrict__ P4,
                                                  float2* __restrict__ EL2,
                                                  float2* __restrict__ ER2) {
    const int tid = threadIdx.x;
    const int lane = tid & 63;
    const int wave = tid >> 6;
    const float4 p = ((const float4*)P4)[lane];
    for (int node = blockIdx.x * 4 + wave; node < N_NODES; node += gridDim.x * 4) {
        float xv = X[node * 64 + lane];
        float e0 = xv * p.x, e1 = xv * p.y, f0 = xv * p.z, f1 = xv * p.w;
#pragma unroll
        for (int off = 32; off; off >>= 1) {
            e0 += __shfl_xor(e0, off);
            e1 += __shfl_xor(e1, off);
            f0 += __shfl_xor(f0, off);
            f1 += __shfl_xor(f1, off);
        }
        if (lane == 0) {
            EL2[node] = make_float2(e0, e1);
            ER2[node] = make_float2(f0, f1);
        }
    }
}

// ---------------------------------------------------------------------------
// LEAN gather: no LDS, no epilogue. Softmax weights + normalized accumulation
// of weighted x[src] rows (AX2) and weighted CSR-ordered E rows (AE).
// Serial loop batched x4 for memory-level parallelism.
// ---------------------------------------------------------------------------
__global__ __launch_bounds__(256) void gather_kernel(const float* __restrict__ X,
                                                     const float2* __restrict__ EL2,
                                                     const float2* __restrict__ ER2,
                                                     const float* __restrict__ E_csr,
                                                     const int* __restrict__ src_csr,
                                                     const int* __restrict__ row_ptr,
                                                     const float2* __restrict__ EE_L,
                                                     float2* __restrict__ AX2,
                                                     float* __restrict__ AE) {
    const int tid = threadIdx.x;
    const int lane = tid & 63;
    const int node = blockIdx.x * 4 + (tid >> 6);
    if (node >= N_NODES) return;
    const float NEG_INF = -__builtin_inff();

    const int beg = row_ptr[node], end = row_ptr[node + 1];
    const int deg = end - beg;
    const float2 er = ER2[node];
    float l0 = 0.f, l1 = 0.f, aX0 = 0.f, aX1 = 0.f, aE = 0.f;

    if (deg <= 64) {
        int sn = 0;
        float lg0 = NEG_INF, lg1 = NEG_INF;
        if (lane < deg) {
            sn = src_csr[beg + lane];          // coalesced
            float2 ee = EE_L[beg + lane];      // coalesced
            float2 el = EL2[sn];               // random 8B
            lg0 = lrelu(el.x + er.x + ee.x);
            lg1 = lrelu(el.y + er.y + ee.y);
        }
        float m0 = lg0, m1 = lg1;
#pragma unroll
        for (int off = 32; off; off >>= 1) {
            m0 = fmaxf(m0, __shfl_xor(m0, off));
            m1 = fmaxf(m1, __shfl_xor(m1, off));
        }
        float w0 = (lane < deg) ? __expf(lg0 - m0) : 0.f;
        float w1 = (lane < deg) ? __expf(lg1 - m1) : 0.f;
        l0 = w0;
        l1 = w1;
#pragma unroll
        for (int off = 32; off; off >>= 1) {
            l0 += __shfl_xor(l0, off);
            l1 += __shfl_xor(l1, off);
        }
        int t = 0;
        for (; t + 4 <= deg; t += 4) {  // 8 independent loads in flight
            int s0 = rl_i(sn, t), s1 = rl_i(sn, t + 1);
            int s2 = rl_i(sn, t + 2), s3 = rl_i(sn, t + 3);
            float x0 = X[s0 * 64 + lane];
            float x1 = X[s1 * 64 + lane];
            float x2 = X[s2 * 64 + lane];
            float x3 = X[s3 * 64 + lane];
            const float* Eb = E_csr + (size_t)(beg + t) * 32 + (lane & 31);
            float e0 = Eb[0], e1 = Eb[32], e2 = Eb[64], e3 = Eb[96];
            float w00 = rl_f(w0, t), w01 = rl_f(w0, t + 1);
            float w02 = rl_f(w0, t + 2), w03 = rl_f(w0, t + 3);
            float w10 = rl_f(w1, t), w11 = rl_f(w1, t + 1);
            float w12 = rl_f(w1, t + 2), w13 = rl_f(w1, t + 3);
            aX0 = fmaf(w00, x0, aX0); aX1 = fmaf(w10, x0, aX1);
            aX0 = fmaf(w01, x1, aX0); aX1 = fmaf(w11, x1, aX1);
            aX0 = fmaf(w02, x2, aX0); aX1 = fmaf(w12, x2, aX1);
            aX0 = fmaf(w03, x3, aX0); aX1 = fmaf(w13, x3, aX1);
            aE = fmaf(lane < 32 ? w00 : w10, e0, aE);
            aE = fmaf(lane < 32 ? w01 : w11, e1, aE);
            aE = fmaf(lane < 32 ? w02 : w12, e2, aE);
            aE = fmaf(lane < 32 ? w03 : w13, e3, aE);
        }
        for (; t < deg; t++) {
            int st = rl_i(sn, t);
            float w0t = rl_f(w0, t), w1t = rl_f(w1, t);
            float xv = X[st * 64 + lane];
            float ev = E_csr[(size_t)(beg + t) * 32 + (lane & 31)];
            aX0 = fmaf(w0t, xv, aX0);
            aX1 = fmaf(w1t, xv, aX1);
            aE = fmaf(lane < 32 ? w0t : w1t, ev, aE);
        }
    } else {
        // general path (rare): chunked two-pass
        float m0 = NEG_INF, m1 = NEG_INF;
        for (int c = beg; c < end; c += 64) {
            int j = c + lane;
            float lg0 = NEG_INF, lg1 = NEG_INF;
            if (j < end) {
                int sn_ = src_csr[j];
                float2 ee = EE_L[j];
                float2 el = EL2[sn_];
                lg0 = lrelu(el.x + er.x + ee.x);
                lg1 = lrelu(el.y + er.y + ee.y);
            }
#pragma unroll
            for (int off = 32; off; off >>= 1) {
                lg0 = fmaxf(lg0, __shfl_xor(lg0, off));
                lg1 = fmaxf(lg1, __shfl_xor(lg1, off));
            }
            m0 = fmaxf(m0, lg0);
            m1 = fmaxf(m1, lg1);
        }
        for (int c = beg; c < end; c += 64) {
            int j = c + lane;
            int sn_ = 0;
            float lg0 = NEG_INF, lg1 = NEG_INF;
            if (j < end) {
                sn_ = src_csr[j];
                float2 ee = EE_L[j];
                float2 el = EL2[sn_];
                lg0 = lrelu(el.x + er.x + ee.x);
                lg1 = lrelu(el.y + er.y + ee.y);
            }
            float w0c = (j < end) ? __expf(lg0 - m0) : 0.f;
            float w1c = (j < end) ? __expf(lg1 - m1) : 0.f;
            float s0 = w0c, s1 = w1c;
#pragma unroll
            for (int off = 32; off; off >>= 1) {
                s0 += __shfl_xor(s0, off);
                s1 += __shfl_xor(s1, off);
            }
            l0 += s0;
            l1 += s1;
            int nch = (end - c) < 64 ? (end - c) : 64;
            for (int t = 0; t < nch; t++) {
                int st = rl_i(sn_, t);
                float w0t = rl_f(w0c, t), w1t = rl_f(w1c, t);
                float xv = X[st * 64 + lane];
                float ev = E_csr[(size_t)(c + t) * 32 + (lane & 31)];
                aX0 = fmaf(w0t, xv, aX0);
                aX1 = fmaf(w1t, xv, aX1);
                aE = fmaf(lane < 32 ? w0t : w1t, ev, aE);
            }
        }
    }
    const float inv0 = l0 > 0.f ? 1.f / l0 : 0.f;
    const float inv1 = l1 > 0.f ? 1.f / l1 : 0.f;
    AX2[node * 64 + lane] = make_float2(aX0 * inv0, aX1 * inv1);
    AE[node * 64 + lane] = aE * (lane < 32 ? inv0 : inv1);
}

// ---------------------------------------------------------------------------
// epilogue: OUT = 0.5*(aX@Wn + aE@We per head) + mean bias; fused next-layer
// el/er. 2 nodes per wave to halve LDS-read traffic.
// ---------------------------------------------------------------------------
__global__ __launch_bounds__(256) void epilogue_kernel(const float2* __restrict__ AX2,
                                                       const float* __restrict__ AE,
                                                       const float* __restrict__ Wn,
                                                       const float* __restrict__ We,
                                                       const float* __restrict__ bias,
                                                       const float* __restrict__ P4next,
                                                       const int has_next,
                                                       float* __restrict__ OUT,
                                                       float2* __restrict__ EL2,
                                                       float2* __restrict__ ER2) {
    __shared__ float4 WnS4[32 * 64];  // 32 KB
    __shared__ float4 WeS4[16 * 64];  // 16 KB
    const int tid = threadIdx.x;
    for (int idx = tid; idx < 32 * 64; idx += 256) {
        int k2 = idx >> 6, l = idx & 63;
        WnS4[idx] = make_float4(Wn[(2 * k2) * 128 + l], Wn[(2 * k2) * 128 + 64 + l],
                                Wn[(2 * k2 + 1) * 128 + l], Wn[(2 * k2 + 1) * 128 + 64 + l]);
    }
    for (int idx = tid; idx < 16 * 64; idx += 256) {
        int k2 = idx >> 6, l = idx & 63;
        WeS4[idx] = make_float4(We[(2 * k2) * 128 + l], We[(2 * k2) * 128 + 64 + l],
                                We[(2 * k2 + 1) * 128 + l], We[(2 * k2 + 1) * 128 + 64 + l]);
    }
    __syncthreads();
    const int lane = tid & 63;
    const int wave = tid >> 6;
    const float b0 = bias[lane], b1 = bias[64 + lane];
    const float4 p = has_next ? ((const float4*)P4next)[lane] : make_float4(0.f, 0.f, 0.f, 0.f);

    for (int base = blockIdx.x * 8 + wave * 2; base < N_NODES; base += gridDim.x * 8) {
        const int n0 = base, n1 = base + 1;  // base even, N_NODES even -> n1 valid
        float2 axa = AX2[n0 * 64 + lane];
        float2 axb = AX2[n1 * 64 + lane];
        float aea = AE[n0 * 64 + lane];
        float aeb = AE[n1 * 64 + lane];
        float r0a = 0.f, r1a = 0.f, r0b = 0.f, r1b = 0.f;
#pragma unroll
        for (int k2 = 0; k2 < 32; k2++) {
            float4 w4 = WnS4[k2 * 64 + lane];
            float a00 = rl_f(axa.x, 2 * k2), a01 = rl_f(axa.x, 2 * k2 + 1);
            float a10 = rl_f(axa.y, 2 * k2), a11 = rl_f(axa.y, 2 * k2 + 1);
            float c00 = rl_f(axb.x, 2 * k2), c01 = rl_f(axb.x, 2 * k2 + 1);
            float c10 = rl_f(axb.y, 2 * k2), c11 = rl_f(axb.y, 2 * k2 + 1);
            r0a = fmaf(a00, w4.x, r0a); r1a = fmaf(a10, w4.y, r1a);
            r0a = fmaf(a01, w4.z, r0a); r1a = fmaf(a11, w4.w, r1a);
            r0b = fmaf(c00, w4.x, r0b); r1b = fmaf(c10, w4.y, r1b);
            r0b = fmaf(c01, w4.z, r0b); r1b = fmaf(c11, w4.w, r1b);
        }
#pragma unroll
        for (int k2 = 0; k2 < 16; k2++) {
            float4 w4 = WeS4[k2 * 64 + lane];
            float a00 = rl_f(aea, 2 * k2), a01 = rl_f(aea, 2 * k2 + 1);
            float a10 = rl_f(aea, 32 + 2 * k2), a11 = rl_f(aea, 32 + 2 * k2 + 1);
            float c00 = rl_f(aeb, 2 * k2), c01 = rl_f(aeb, 2 * k2 + 1);
            float c10 = rl_f(aeb, 32 + 2 * k2), c11 = rl_f(aeb, 32 + 2 * k2 + 1);
            r0a = fmaf(a00, w4.x, r0a); r1a = fmaf(a10, w4.y, r1a);
            r0a = fmaf(a01, w4.z, r0a); r1a = fmaf(a11, w4.w, r1a);
            r0b = fmaf(c00, w4.x, r0b); r1b = fmaf(c10, w4.y, r1b);
            r0b = fmaf(c01, w4.z, r0b); r1b = fmaf(c11, w4.w, r1b);
        }
        float outa = 0.5f * (r0a + b0 + r1a + b1);
        float outb = 0.5f * (r0b + b0 + r1b + b1);
        OUT[n0 * 64 + lane] = outa;
        OUT[n1 * 64 + lane] = outb;
        if (has_next) {
            float e0a = outa * p.x, e1a = outa * p.y, f0a = outa * p.z, f1a = outa * p.w;
            float e0b = outb * p.x, e1b = outb * p.y, f0b = outb * p.z, f1b = outb * p.w;
#pragma unroll
            for (int off = 32; off; off >>= 1) {
                e0a += __shfl_xor(e0a, off); e1a += __shfl_xor(e1a, off);
                f0a += __shfl_xor(f0a, off); f1a += __shfl_xor(f1a, off);
                e0b += __shfl_xor(e0b, off); e1b += __shfl_xor(e1b, off);
                f0b += __shfl_xor(f0b, off); f1b += __shfl_xor(f1b, off);
            }
            if (lane == 0) {
                EL2[n0] = make_float2(e0a, e1a);
                ER2[n0] = make_float2(f0a, f1a);
                EL2[n1] = make_float2(e0b, e1b);
                ER2[n1] = make_float2(f0b, f1b);
            }
        }
    }
}

// ---------------------------------------------------------------------------
extern "C" void kernel_launch(void* const* d_in, const int* in_sizes, int n_in,
                              void* d_out, int out_size, void* d_ws, size_t ws_size,
                              hipStream_t stream) {
    const float* x = (const float*)d_in[0];
    const float* e = (const float*)d_in[1];
    const int* src = (const int*)d_in[2];
    const int* dst = (const int*)d_in[3];

    // Only the LAST snapshot contributes to the output (decoded[-1]).
    const float* x1 = x + (size_t)1 * N_NODES * 64;
    const float* e1 = e + (size_t)1 * N_EDGES * 32;
    const int* src1 = src + N_EDGES;
    const int* dst1 = dst + N_EDGES;

    int we2d_idx, dec0_b, dec1_b;
    if (in_sizes[16] == 64 * 64 && in_sizes[17] == 64 * 128) {
        we2d_idx = 16; dec0_b = 17; dec1_b = 23;
    } else {
        dec0_b = 16; dec1_b = 22; we2d_idx = 28;
    }
    auto P = [&](int i) { return (const float*)d_in[i]; };

    // workspace layout (bytes, 64-aligned blocks)
    char* ws = (char*)d_ws;
    int* cnt      = (int*)(ws + 0);          //     80,000
    int* row_ptr  = (int*)(ws + 80000);      //     80,004
    int* pos      = (int*)(ws + 160064);     //    400,000
    int* bsum     = (int*)(ws + 560064);     //        512
    float* q      = (float*)(ws + 560576);   //      1,024
    int* src_csr  = (int*)(ws + 561600);     //    400,000
    float* e_csr  = (float*)(ws + 961600);   // 12,800,000
    float* ee_csr = (float*)(ws + 13761600); //  3,200,000
    float* p4_all = (float*)(ws + 16961600); //      4,096
    float* el     = (float*)(ws + 16965696); //    160,000
    float* er     = (float*)(ws + 17125696); //    160,000
    float* ax     = (float*)(ws + 17285696); // 10,240,000
    float* ae     = (float*)(ws + 27525696); //  5,120,000
    float* h      = (float*)(ws + 32645696); //  5,120,000
    float* wcomb  = (float*)(ws + 37765696); //     32,768
    // total ~37.8 MB

    hipMemsetAsync(cnt, 0, N_NODES * sizeof(int), stream);
    const int EB = (N_EDGES + 255) / 256;
    const int SB = (N_NODES + 255) / 256;  // 79
    count_kernel<<<EB, 256, 0, stream>>>(dst1, cnt, pos);
    scanA_kernel<<<SB, 256, 0, stream>>>(cnt, bsum);
    scanC_kernel<<<SB, 256, 0, stream>>>(cnt, bsum, row_ptr);

    // CSR-ordered per-edge arrays (removes indirection from gather hot loop)
    permE_kernel<<<(N_EDGES * 32) / 256, 256, 0, stream>>>(e1, src1, dst1, pos,
                                                           row_ptr, e_csr, src_csr);
    q_kernel<<<1, 256, 0, stream>>>(P(5), P(8), P(11), P(14),
                                    P(dec0_b + 1), P(dec0_b + 4),
                                    P(dec1_b + 1), P(dec1_b + 4), q);
    ee_kernel<<<(N_EDGES + 31) / 32, 256, 0, stream>>>(e1, dst1, pos, row_ptr, q, ee_csr);
    comb_kernel<<<32, 256, 0, stream>>>(P(we2d_idx), P(dec0_b + 0), wcomb);
    p4_kernel<<<4, 256, 0, stream>>>(P(4), P(6), P(7),
                                     P(10), P(12), P(13),
                                     wcomb, P(dec0_b + 2), P(dec0_b + 3),
                                     P(dec1_b + 0), P(dec1_b + 2), P(dec1_b + 3),
                                     p4_all);
    // layer-0 el/er
    elr_kernel<<<1280, 256, 0, stream>>>(x1, p4_all, (float2*)el, (float2*)er);

    const int NB_G = (N_NODES + 3) / 4;  // 5000: exactly 1 node per wave
    const int NB_E = 768;                // 48KB LDS -> 3 blocks/CU

    auto run_layer = [&](const float* Xin, const float* Wn, const float* We_,
                         const float* b_, int L, float* Out) {
        gather_kernel<<<NB_G, 256, 0, stream>>>(
            Xin, (const float2*)el, (const float2*)er, e_csr, src_csr, row_ptr,
            (const float2*)(ee_csr) + (size_t)L * N_EDGES, (float2*)ax, ae);
        epilogue_kernel<<<NB_E, 256, 0, stream>>>(
            (const float2*)ax, ae, Wn, We_, b_, p4_all + (L + 1) * 256, (L < 3) ? 1 : 0,
            Out, (float2*)el, (float2*)er);
    };

    // single h buffer: epilogue(L) only reads ax/ae, so in-place over Xin is safe
    run_layer(x1, P(4), P(5), P(9), 0, h);
    run_layer(h, P(10), P(11), P(15), 1, h);
    run_layer(h, wcomb, P(dec0_b + 1), P(dec0_b + 5), 2, h);
    run_layer(h, P(dec1_b + 0), P(dec1_b + 1), P(dec1_b + 5), 3, (float*)d_out);
}